// Round 2
// baseline (84.712 us; speedup 1.0000x reference)
//
#include <hip/hip_runtime.h>

#define SIGMA  1.0f
#define LOG2E  1.4426950408889634f
#define EPSF   1e-8f

// HW transcendentals: v_exp_f32 computes 2^x, v_log_f32 computes log2(x).
#define EXP2F(x) __builtin_amdgcn_exp2f(x)
#define LOG2F(x) __builtin_amdgcn_logf(x)

// One block per query. 256 threads = 4 waves.
// Thread layout: j = tid & 127 (column/doc), r0 = tid >> 7 (row phase 0/1),
// rows i = r0, r0+2, ... < L. LDS broadcast for row operands.
__global__ __launch_bounds__(256) void ndcg_loss_kernel(
    const float* __restrict__ scores,
    const int*   __restrict__ relevances,
    const int*   __restrict__ qlen,
    float*       __restrict__ out,
    float invB)
{
    __shared__ float s_sc[128];
    __shared__ float s_g[128];
    __shared__ int   s_cnt[5];
    __shared__ float s_red[4][2];

    const int b   = blockIdx.x;
    const int tid = threadIdx.x;
    const int L   = qlen[b];

    if (tid < 5) s_cnt[tid] = 0;
    __syncthreads();

    if (tid < 128) {
        float sc = scores[b * 128 + tid];
        int   r  = relevances[b * 128 + tid];
        r = min(max(r, 0), 4);               // safety clamp for LDS index
        s_sc[tid] = sc;
        bool valid = (tid < L);
        // gains = 2^rel - 1, exact for integer grades
        s_g[tid] = valid ? (float)((1 << r) - 1) : 0.0f;
        if (valid) atomicAdd(&s_cnt[r], 1);
    }
    __syncthreads();

    // ---- pairwise sum: num = sum_{i,j<L} |g_i - g_j| * log2(sigmoid(s_i - s_j))
    float num = 0.0f;
    {
        const int j  = tid & 127;
        const int r0 = tid >> 7;
        if (j < L) {
            const float sj = s_sc[j];
            const float gj = s_g[j];
            for (int i = r0; i < L; i += 2) {
                float d  = s_sc[i] - sj;              // LDS broadcast read
                float dg = fabsf(s_g[i] - gj);
                float y  = d * (SIGMA * LOG2E);
                // log2(sigmoid(x)) = min(y,0) - log2(1 + 2^{-|y|}),  y = x*log2(e)
                float lp = fminf(y, 0.0f) - LOG2F(1.0f + EXP2F(-fabsf(y)));
                num += dg * lp;
            }
        }
    }

    // ---- ideal DCG via grade histogram (gains sorted desc = threshold lookup)
    float idcg = 0.0f;
    if (tid < 128 && tid < L) {
        int c4 = s_cnt[4], c3 = s_cnt[3], c2 = s_cnt[2], c1 = s_cnt[1];
        int t1 = c4, t2 = t1 + c3, t3 = t2 + c2, t4 = t3 + c1;
        float g = (tid < t1) ? 15.0f :
                  (tid < t2) ?  7.0f :
                  (tid < t3) ?  3.0f :
                  (tid < t4) ?  1.0f : 0.0f;
        idcg = g / LOG2F((float)(tid + 2));           // discount 1/log2(rank+2)
    }

    // ---- block reduction of (num, idcg): wave shuffle then cross-wave LDS
    #pragma unroll
    for (int o = 32; o > 0; o >>= 1) {
        num  += __shfl_down(num,  o, 64);
        idcg += __shfl_down(idcg, o, 64);
    }
    const int w = tid >> 6;
    if ((tid & 63) == 0) { s_red[w][0] = num; s_red[w][1] = idcg; }
    __syncthreads();

    if (tid == 0) {
        float n = s_red[0][0] + s_red[1][0] + s_red[2][0] + s_red[3][0];
        float d = s_red[0][1] + s_red[1][1] + s_red[2][1] + s_red[3][1];
        float per_query = -n / (d + EPSF);
        atomicAdd(out, per_query * invB);
    }
}

extern "C" void kernel_launch(void* const* d_in, const int* in_sizes, int n_in,
                              void* d_out, int out_size, void* d_ws, size_t ws_size,
                              hipStream_t stream)
{
    const float* scores     = (const float*)d_in[0];
    const int*   relevances = (const int*)  d_in[1];
    const int*   qlen       = (const int*)  d_in[2];
    float*       out        = (float*)d_out;

    const int B = in_sizes[2];          // 2048
    // d_out is poisoned to 0xAA before every timed launch — zero it ourselves.
    (void)hipMemsetAsync(out, 0, sizeof(float) * out_size, stream);
    ndcg_loss_kernel<<<B, 256, 0, stream>>>(scores, relevances, qlen, out,
                                            1.0f / (float)B);
}